// Round 4
// baseline (1219.779 us; speedup 1.0000x reference)
//
#include <hip/hip_runtime.h>
#include <hip/hip_bf16.h>
#include <stdint.h>

#define NNODES 50000
#define NEDGES 800000
#define HC 256

typedef unsigned short u16;
typedef __attribute__((ext_vector_type(4))) float f32x4;

__device__ __forceinline__ float b2f(u16 v) {
    return __uint_as_float(((unsigned)v) << 16);
}
__device__ __forceinline__ u16 f2b(float f) {
    unsigned u = __float_as_uint(f);
    u += 0x7fff + ((u >> 16) & 1);
    return (u16)(u >> 16);
}

// ---------------- workspace zero-init ----------------
__global__ void zero_init(unsigned* __restrict__ p, long nwords) {
    long i = (long)blockIdx.x * blockDim.x + threadIdx.x;
    long stride = (long)gridDim.x * blockDim.x;
    for (; i < nwords; i += stride) p[i] = 0u;
}

// ---------------- dtype detection ----------------
// Examine first 1024 32-bit words of x. For true-bf16 data, the LOW 16 bits of
// each word are a sane bf16 (~N(0,1)); for fp32 data they are mantissa garbage
// (sane-exponent probability ~7%). flag: 1 = bf16 inputs, 0 = fp32 inputs.
__global__ void detect_dtype(const unsigned* __restrict__ xbits, int* __restrict__ flag) {
    __shared__ int cnt;
    if (threadIdx.x == 0) cnt = 0;
    __syncthreads();
    int sane = 0;
    for (int i = threadIdx.x; i < 1024; i += 256) {
        unsigned lo = xbits[i] & 0xffffu;
        int e = (int)((lo >> 7) & 0xff);
        if (e >= 117 && e <= 133) sane++;  // |v| in [2^-10, 2^6]
    }
    atomicAdd(&cnt, sane);
    __syncthreads();
    if (threadIdx.x == 0) *flag = (cnt >= 512) ? 1 : 0;
}

// ---------------- canonicalize float input -> internal bf16 ----------------
__global__ void cvt_bf16(const void* __restrict__ src, u16* __restrict__ dst, int n,
                         const int* __restrict__ flag) {
    int isbf16 = *flag;
    int i = blockIdx.x * 256 + threadIdx.x;
    int stride = gridDim.x * 256;
    if (isbf16) {
        const u16* s = (const u16*)src;
        for (; i < n; i += stride) dst[i] = s[i];
    } else {
        const float* s = (const float*)src;
        for (; i < n; i += stride) dst[i] = f2b(s[i]);
    }
}

// out[f][h] = sum_c W[f*256 + h*64 + c] * att[h*64 + c],  f < R   (bf16 internal)
__global__ void proj_weight(const u16* __restrict__ W, const u16* __restrict__ att,
                            float* __restrict__ out, int R) {
    int i = blockIdx.x * 256 + threadIdx.x;
    if (i >= R * 4) return;
    int f = i >> 2, h = i & 3;
    float s = 0.f;
    for (int c = 0; c < 64; c++)
        s += b2f(W[f * 256 + h * 64 + c]) * b2f(att[h * 64 + c]);
    out[i] = s;
}

// ---------------- edge pass (bf16 internal eattr) ----------------
__global__ __launch_bounds__(256) void edge_pass(
    const u16* __restrict__ eattr, const int* __restrict__ edst,
    const float* __restrict__ ve1, const float* __restrict__ ve2,
    u16* __restrict__ ae1, u16* __restrict__ ae2,
    float* __restrict__ sum1, float* __restrict__ sum2, int* __restrict__ deg) {
    int e = blockIdx.x * 256 + threadIdx.x;
    if (e >= NEDGES) return;
    const uint4* p = (const uint4*)(eattr + (long)e * 16);
    uint4 q0 = p[0], q1 = p[1];
    float a[16];
    unsigned w0[8] = {q0.x, q0.y, q0.z, q0.w, q1.x, q1.y, q1.z, q1.w};
    #pragma unroll
    for (int j = 0; j < 8; j++) { a[2*j] = b2f((u16)(w0[j] & 0xffff)); a[2*j+1] = b2f((u16)(w0[j] >> 16)); }
    int d = edst[e];
    atomicAdd(&deg[d], 1);
    #pragma unroll
    for (int h = 0; h < 4; h++) {
        float s1 = 0.f, s2 = 0.f;
        #pragma unroll
        for (int f = 0; f < 16; f++) {
            s1 += a[f] * ve1[f * 4 + h];
            s2 += a[f] * ve2[f * 4 + h];
        }
        ae1[e * 4 + h] = f2b(s1);
        ae2[e * 4 + h] = f2b(s2);
        atomicAdd(&sum1[d * 4 + h], s1);
        atomicAdd(&sum2[d * 4 + h], s2);
    }
}

// ---------------- CSR build ----------------
__global__ void block_sum(const int* __restrict__ deg, int* __restrict__ bsums, int n) {
    __shared__ int lds[256];
    int i = blockIdx.x * 256 + threadIdx.x;
    lds[threadIdx.x] = (i < n) ? deg[i] : 0;
    __syncthreads();
    for (int s = 128; s; s >>= 1) {
        if (threadIdx.x < s) lds[threadIdx.x] += lds[threadIdx.x + s];
        __syncthreads();
    }
    if (threadIdx.x == 0) bsums[blockIdx.x] = lds[0];
}

__global__ void scan_bsums(const int* __restrict__ bsums, int* __restrict__ boffs, int nb) {
    __shared__ int lds[256];
    int t = threadIdx.x;
    int v = (t < nb) ? bsums[t] : 0;
    lds[t] = v;
    __syncthreads();
    for (int s = 1; s < 256; s <<= 1) {
        int u = (t >= s) ? lds[t - s] : 0;
        __syncthreads();
        lds[t] += u;
        __syncthreads();
    }
    boffs[t] = lds[t] - v;  // exclusive
}

__global__ void write_offsets(const int* __restrict__ deg, const int* __restrict__ boffs,
                              int* __restrict__ off, int* __restrict__ cursor, int n) {
    __shared__ int lds[256];
    int t = threadIdx.x;
    int i = blockIdx.x * 256 + t;
    int v = (i < n) ? deg[i] : 0;
    lds[t] = v;
    __syncthreads();
    for (int s = 1; s < 256; s <<= 1) {
        int u = (t >= s) ? lds[t - s] : 0;
        __syncthreads();
        lds[t] += u;
        __syncthreads();
    }
    int exc = lds[t] - v + boffs[blockIdx.x];
    if (i < n) { off[i] = exc; cursor[i] = exc; }
}

__global__ void csr_fill(const int* __restrict__ edst, int* __restrict__ cursor,
                         int* __restrict__ edges) {
    int e = blockIdx.x * 256 + threadIdx.x;
    if (e >= NEDGES) return;
    int p = atomicAdd(&cursor[edst[e]], 1);
    edges[p] = e;
}

// ---------------- VALU GEMM: out[M][256] = A[M][K] @ W[K][256]  (bf16 internal) ------
template <int K>
__global__ __launch_bounds__(256) void gemm_valu(const u16* __restrict__ A,
                                                 const u16* __restrict__ W,
                                                 u16* __restrict__ out) {
    constexpr int LDK = K + 4;
    __shared__ float a_lds[16][LDK];
    int t = threadIdx.x;
    long row0 = (long)blockIdx.x * 16;
    constexpr int PER = (16 * K) / 256;
    const u16* Abase = A + row0 * K;
    #pragma unroll
    for (int i = 0; i < PER; i += 4) {
        int flat = t * PER + i;
        int r = flat / K, k = flat % K;
        ushort4 v = *(const ushort4*)(Abase + flat);
        a_lds[r][k + 0] = b2f(v.x);
        a_lds[r][k + 1] = b2f(v.y);
        a_lds[r][k + 2] = b2f(v.z);
        a_lds[r][k + 3] = b2f(v.w);
    }
    __syncthreads();
    int cg = t & 63, rg = t >> 6;
    int c0 = cg * 4;
    float acc[4][4] = {};
    for (int k = 0; k < K; k += 4) {
        float wv[4][4];
        #pragma unroll
        for (int j = 0; j < 4; j++) {
            uint2 wq = *(const uint2*)(W + (long)(k + j) * 256 + c0);
            wv[j][0] = b2f((u16)(wq.x & 0xffff));
            wv[j][1] = b2f((u16)(wq.x >> 16));
            wv[j][2] = b2f((u16)(wq.y & 0xffff));
            wv[j][3] = b2f((u16)(wq.y >> 16));
        }
        #pragma unroll
        for (int i = 0; i < 4; i++) {
            int r = rg * 4 + i;
            f32x4 av = *(const f32x4*)&a_lds[r][k];
            #pragma unroll
            for (int j = 0; j < 4; j++) {
                #pragma unroll
                for (int cc = 0; cc < 4; cc++)
                    acc[i][cc] += av[j] * wv[j][cc];
            }
        }
    }
    u16* orow = out + row0 * HC;
    #pragma unroll
    for (int i = 0; i < 4; i++) {
        int r = rg * 4 + i;
        uint2 ov;
        ov.x = (unsigned)f2b(acc[i][0]) | ((unsigned)f2b(acc[i][1]) << 16);
        ov.y = (unsigned)f2b(acc[i][2]) | ((unsigned)f2b(acc[i][3]) << 16);
        *(uint2*)(orow + (long)r * HC + c0) = ov;
    }
}

// ---------------- a_s/a_d projection ----------------
template <int K>
__global__ __launch_bounds__(256) void proj_att(const u16* __restrict__ X,
                                                const float* __restrict__ us,
                                                const float* __restrict__ ud,
                                                float* __restrict__ as_, float* __restrict__ ad_) {
    int wid = (blockIdx.x * 256 + threadIdx.x) >> 6;
    int lane = threadIdx.x & 63;
    if (wid >= NNODES) return;
    float pas[4] = {0.f, 0.f, 0.f, 0.f}, pad[4] = {0.f, 0.f, 0.f, 0.f};
    const u16* row = X + (long)wid * K;
    for (int f = lane; f < K; f += 64) {
        float xv = b2f(row[f]);
        #pragma unroll
        for (int h = 0; h < 4; h++) {
            pas[h] += xv * us[f * 4 + h];
            pad[h] += xv * ud[f * 4 + h];
        }
    }
    #pragma unroll
    for (int h = 0; h < 4; h++) {
        for (int o = 32; o; o >>= 1) {
            pas[h] += __shfl_down(pas[h], o);
            pad[h] += __shfl_down(pad[h], o);
        }
    }
    if (lane == 0) {
        #pragma unroll
        for (int h = 0; h < 4; h++) {
            as_[wid * 4 + h] = pas[h];
            ad_[wid * 4 + h] = pad[h];
        }
    }
}

// ---------------- GAT attention + aggregation (one wave per dst node) --------
__global__ __launch_bounds__(256) void gat_agg(
    const u16* __restrict__ xs, const float* __restrict__ as_, const float* __restrict__ ad_,
    const u16* __restrict__ ae, const float* __restrict__ sumae,
    const int* __restrict__ off, const int* __restrict__ cur, const int* __restrict__ edges,
    const int* __restrict__ esrc, const u16* __restrict__ bias, u16* __restrict__ out) {
    int wid = (blockIdx.x * 256 + threadIdx.x) >> 6;
    if (wid >= NNODES) return;
    int lane = threadIdx.x & 63;
    int h = lane >> 4;
    int d = wid;
    int st = off[d], en = cur[d];
    float degf = (float)(en - st);
    float adv = ad_[d * 4 + h];
    float asv = as_[d * 4 + h];
    float aes = sumae[d * 4 + h] / fmaxf(degf, 1.0f);
    float l0 = asv + adv + aes;
    l0 = (l0 > 0.f) ? l0 : 0.2f * l0;
    float m = l0, s = 1.0f;
    float a0, a1, a2, a3;
    {
        uint2 v = *(const uint2*)(xs + (long)d * HC + lane * 4);
        a0 = b2f((u16)(v.x & 0xffff)); a1 = b2f((u16)(v.x >> 16));
        a2 = b2f((u16)(v.y & 0xffff)); a3 = b2f((u16)(v.y >> 16));
    }
    for (int i = st; i < en; i++) {
        int e = edges[i];
        int src = esrc[e];
        float lg = as_[src * 4 + h] + adv + b2f(ae[e * 4 + h]);
        lg = (lg > 0.f) ? lg : 0.2f * lg;
        float mn = fmaxf(m, lg);
        float sc = __expf(m - mn), w = __expf(lg - mn);
        uint2 v = *(const uint2*)(xs + (long)src * HC + lane * 4);
        float x0 = b2f((u16)(v.x & 0xffff)), x1 = b2f((u16)(v.x >> 16));
        float x2 = b2f((u16)(v.y & 0xffff)), x3 = b2f((u16)(v.y >> 16));
        s = s * sc + w;
        a0 = a0 * sc + w * x0;
        a1 = a1 * sc + w * x1;
        a2 = a2 * sc + w * x2;
        a3 = a3 * sc + w * x3;
        m = mn;
    }
    float inv = 1.0f / (s + 1e-16f);
    int cb = lane * 4;
    u16 o0 = f2b(a0 * inv + b2f(bias[cb + 0]));
    u16 o1 = f2b(a1 * inv + b2f(bias[cb + 1]));
    u16 o2 = f2b(a2 * inv + b2f(bias[cb + 2]));
    u16 o3 = f2b(a3 * inv + b2f(bias[cb + 3]));
    uint2 ov;
    ov.x = (unsigned)o0 | ((unsigned)o1 << 16);
    ov.y = (unsigned)o2 | ((unsigned)o3 << 16);
    *(uint2*)(out + (long)d * HC + cb) = ov;
}

// ---------------- BatchNorm (batch stats) + ReLU ----------------
__global__ void bn_stats(const u16* __restrict__ h, float* __restrict__ stats) {
    int c = threadIdx.x;
    float s = 0.f, q = 0.f;
    for (int r = blockIdx.x; r < NNODES; r += gridDim.x) {
        float v = b2f(h[(long)r * HC + c]);
        s += v;
        q += v * v;
    }
    atomicAdd(&stats[c], s);
    atomicAdd(&stats[256 + c], q);
}

__global__ void bn_apply(u16* __restrict__ h, const float* __restrict__ stats,
                         const u16* __restrict__ g, const u16* __restrict__ be) {
    long i = (long)blockIdx.x * 256 + threadIdx.x;
    if (i >= (long)NNODES * HC) return;
    int c = (int)(i & 255);
    float mu = stats[c] * (1.0f / NNODES);
    float var = stats[256 + c] * (1.0f / NNODES) - mu * mu;
    var = fmaxf(var, 0.f);
    float rs = rsqrtf(var + 1e-5f);
    float v = b2f(h[i]);
    float y = b2f(g[c]) * (v - mu) * rs + b2f(be[c]);
    h[i] = f2b(fmaxf(y, 0.f));
}

// ---------------- output head (dtype-dispatched store) ----------------
__global__ __launch_bounds__(256) void out_head(const u16* __restrict__ h,
                                                const u16* __restrict__ wout,
                                                const u16* __restrict__ bout,
                                                void* __restrict__ y,
                                                const int* __restrict__ flag) {
    int wid = (blockIdx.x * 256 + threadIdx.x) >> 6;
    int lane = threadIdx.x & 63;
    if (wid >= NNODES) return;
    const u16* r = h + (long)wid * HC + lane * 4;
    float p = b2f(r[0]) * b2f(wout[lane * 4 + 0]) + b2f(r[1]) * b2f(wout[lane * 4 + 1]) +
              b2f(r[2]) * b2f(wout[lane * 4 + 2]) + b2f(r[3]) * b2f(wout[lane * 4 + 3]);
    for (int o = 32; o; o >>= 1) p += __shfl_down(p, o);
    if (lane == 0) {
        float v = p + b2f(bout[0]);
        if (*flag) ((u16*)y)[wid] = f2b(v);
        else       ((float*)y)[wid] = v;
    }
}

extern "C" void kernel_launch(void* const* d_in, const int* in_sizes, int n_in,
                              void* d_out, int out_size, void* d_ws, size_t ws_size,
                              hipStream_t stream) {
    (void)in_sizes; (void)n_in; (void)out_size; (void)ws_size;
    const void* x_raw     = d_in[0];
    const int*  esrc      = (const int*)d_in[1];
    const int*  edst      = (const int*)d_in[2];
    const void* eattr_raw = d_in[3];

    char* ws = (char*)d_ws;
    size_t o = 0;
    auto alloc = [&](size_t bytes) -> char* {
        o = (o + 255) & ~(size_t)255;
        char* p = ws + o;
        o += bytes;
        return p;
    };
    int* dflag = (int*)alloc(256);
    // canonical bf16 copies of all float inputs
    u16* xb   = (u16*)alloc((size_t)NNODES * 64 * 2);
    u16* eab  = (u16*)alloc((size_t)NEDGES * 16 * 2);
    u16* cparams[18];  // W1,atts1,attd1,We1,atte1,b1,g1,be1,W2,atts2,attd2,We2,atte2,b2,g2,be2,Wout,bout
    const int psize[18] = {64*256, 256, 256, 16*256, 256, 256, 256, 256,
                           256*256, 256, 256, 16*256, 256, 256, 256, 256, 256, 1};
    for (int i = 0; i < 18; i++) cparams[i] = (u16*)alloc((size_t)psize[i] * 2);
    u16 *W1b = cparams[0], *atts1b = cparams[1], *attd1b = cparams[2], *We1b = cparams[3],
        *atte1b = cparams[4], *b1b = cparams[5], *g1b = cparams[6], *be1b = cparams[7],
        *W2b = cparams[8], *atts2b = cparams[9], *attd2b = cparams[10], *We2b = cparams[11],
        *atte2b = cparams[12], *b2b = cparams[13], *g2b = cparams[14], *be2b = cparams[15],
        *Woutb = cparams[16], *boutb = cparams[17];
    // projected weights (fp32)
    float* ve1 = (float*)alloc(64 * 4);
    float* ve2 = (float*)alloc(64 * 4);
    float* us1 = (float*)alloc(256 * 4);
    float* ud1 = (float*)alloc(256 * 4);
    float* us2 = (float*)alloc(1024 * 4);
    float* ud2 = (float*)alloc(1024 * 4);
    // zero zone (contiguous): deg, sum1, sum2, stats1, stats2
    int* deg = (int*)alloc((size_t)NNODES * 4);
    float* sum1 = (float*)alloc((size_t)NNODES * 16);
    float* sum2 = (float*)alloc((size_t)NNODES * 16);
    float* stats1 = (float*)alloc(512 * 4);
    float* stats2 = (float*)alloc(512 * 4);
    size_t zero_end = o;
    size_t zero_begin = (size_t)((char*)deg - ws);
    // rest
    int* off = (int*)alloc((size_t)NNODES * 4);
    int* cursor = (int*)alloc((size_t)NNODES * 4);
    int* bsums = (int*)alloc(256 * 4);
    int* boffs = (int*)alloc(256 * 4);
    int* csr = (int*)alloc((size_t)NEDGES * 4);
    u16* ae1 = (u16*)alloc((size_t)NEDGES * 8);
    u16* ae2 = (u16*)alloc((size_t)NEDGES * 8);
    float* as_ = (float*)alloc((size_t)NNODES * 16);
    float* ad_ = (float*)alloc((size_t)NNODES * 16);
    u16* bufA = (u16*)alloc((size_t)NNODES * HC * 2);  // xs1, then xs2
    u16* bufB = (u16*)alloc((size_t)NNODES * HC * 2);  // h1, then h2

    long zwords = (long)((zero_end - zero_begin) / 4);
    zero_init<<<512, 256, 0, stream>>>((unsigned*)(ws + zero_begin), zwords);
    detect_dtype<<<1, 256, 0, stream>>>((const unsigned*)x_raw, dflag);

    auto cvt = [&](const void* src, u16* dst, int n) {
        int blocks = (n + 255) / 256;
        if (blocks > 2048) blocks = 2048;
        cvt_bf16<<<blocks, 256, 0, stream>>>(src, dst, n, dflag);
    };
    cvt(x_raw, xb, NNODES * 64);
    cvt(eattr_raw, eab, NEDGES * 16);
    for (int i = 0; i < 18; i++) cvt(d_in[4 + i], cparams[i], psize[i]);

    proj_weight<<<1, 256, 0, stream>>>(We1b, atte1b, ve1, 16);
    proj_weight<<<1, 256, 0, stream>>>(We2b, atte2b, ve2, 16);
    proj_weight<<<1, 256, 0, stream>>>(W1b, atts1b, us1, 64);
    proj_weight<<<1, 256, 0, stream>>>(W1b, attd1b, ud1, 64);
    proj_weight<<<4, 256, 0, stream>>>(W2b, atts2b, us2, 256);
    proj_weight<<<4, 256, 0, stream>>>(W2b, attd2b, ud2, 256);

    int eblocks = (NEDGES + 255) / 256;
    edge_pass<<<eblocks, 256, 0, stream>>>(eab, edst, ve1, ve2, ae1, ae2, sum1, sum2, deg);
    int nb = (NNODES + 255) / 256;  // 196
    block_sum<<<nb, 256, 0, stream>>>(deg, bsums, NNODES);
    scan_bsums<<<1, 256, 0, stream>>>(bsums, boffs, nb);
    write_offsets<<<nb, 256, 0, stream>>>(deg, boffs, off, cursor, NNODES);
    csr_fill<<<eblocks, 256, 0, stream>>>(edst, cursor, csr);

    int mtiles = NNODES / 16;                 // 3125
    int wblocks = (NNODES * 64 + 255) / 256;  // 12500

    // layer 1  (xb: K=64)
    gemm_valu<64><<<mtiles, 256, 0, stream>>>(xb, W1b, bufA);
    proj_att<64><<<wblocks, 256, 0, stream>>>(xb, us1, ud1, as_, ad_);
    gat_agg<<<wblocks, 256, 0, stream>>>(bufA, as_, ad_, ae1, sum1, off, cursor, csr, esrc, b1b, bufB);
    bn_stats<<<256, 256, 0, stream>>>(bufB, stats1);
    bn_apply<<<(NNODES * HC + 255) / 256, 256, 0, stream>>>(bufB, stats1, g1b, be1b);

    // layer 2  (h1 = bufB: K=256)
    gemm_valu<256><<<mtiles, 256, 0, stream>>>(bufB, W2b, bufA);
    proj_att<256><<<wblocks, 256, 0, stream>>>(bufB, us2, ud2, as_, ad_);
    gat_agg<<<wblocks, 256, 0, stream>>>(bufA, as_, ad_, ae2, sum2, off, cursor, csr, esrc, b2b, bufB);
    bn_stats<<<256, 256, 0, stream>>>(bufB, stats2);
    bn_apply<<<(NNODES * HC + 255) / 256, 256, 0, stream>>>(bufB, stats2, g2b, be2b);

    out_head<<<wblocks, 256, 0, stream>>>(bufB, Woutb, boutb, d_out, dflag);
}

// Round 5
// 787.024 us; speedup vs baseline: 1.5499x; 1.5499x over previous
//
#include <hip/hip_runtime.h>
#include <hip/hip_bf16.h>
#include <stdint.h>

#define NNODES 50000
#define NEDGES 800000
#define HC 256

typedef unsigned short u16;
typedef __attribute__((ext_vector_type(8))) short bf16x8;
typedef __attribute__((ext_vector_type(4))) float f32x4;

__device__ __forceinline__ float b2f(u16 v) {
    return __uint_as_float(((unsigned)v) << 16);
}
__device__ __forceinline__ u16 f2b(float f) {
    unsigned u = __float_as_uint(f);
    u += 0x7fff + ((u >> 16) & 1);
    return (u16)(u >> 16);
}

// param table: W1,atts1,attd1,We1,atte1,b1,g1,be1,W2,atts2,attd2,We2,atte2,b2,g2,be2,Wout,bout
__device__ __constant__ int dPO[19] = {0,16384,16640,16896,20992,21248,21504,21760,22016,
                                       87552,87808,88064,92160,92416,92672,92928,93184,93440,93441};
static const int hPO[19] = {0,16384,16640,16896,20992,21248,21504,21760,22016,
                            87552,87808,88064,92160,92416,92672,92928,93184,93440,93441};
#define TOTP 93441

// ---------------- workspace zero-init ----------------
__global__ void zero_init(unsigned* __restrict__ p, long nwords) {
    long i = (long)blockIdx.x * blockDim.x + threadIdx.x;
    long stride = (long)gridDim.x * blockDim.x;
    for (; i < nwords; i += stride) p[i] = 0u;
}

// ---------------- dtype detection (1 = bf16 inputs, 0 = fp32 inputs) ----------------
__global__ void detect_dtype(const unsigned* __restrict__ xbits, int* __restrict__ flag) {
    __shared__ int cnt;
    if (threadIdx.x == 0) cnt = 0;
    __syncthreads();
    int sane = 0;
    for (int i = threadIdx.x; i < 1024; i += 256) {
        unsigned lo = xbits[i] & 0xffffu;
        int e = (int)((lo >> 7) & 0xff);
        if (e >= 117 && e <= 133) sane++;
    }
    atomicAdd(&cnt, sane);
    __syncthreads();
    if (threadIdx.x == 0) *flag = (cnt >= 512) ? 1 : 0;
}

// ---------------- canonicalize float input -> internal bf16 ----------------
__global__ void cvt_bf16(const void* __restrict__ src, u16* __restrict__ dst, int n,
                         const int* __restrict__ flag) {
    int isbf16 = *flag;
    int i = blockIdx.x * 256 + threadIdx.x;
    int stride = gridDim.x * 256;
    if (isbf16) {
        const u16* s = (const u16*)src;
        for (; i < n; i += stride) dst[i] = s[i];
    } else {
        const float* s = (const float*)src;
        for (; i < n; i += stride) dst[i] = f2b(s[i]);
    }
}

struct Ptrs18 { const void* s[18]; };
__global__ void cvt_params(Ptrs18 p, u16* __restrict__ dst, const int* __restrict__ flag) {
    int i = blockIdx.x * 256 + threadIdx.x;
    if (i >= TOTP) return;
    int isbf16 = *flag;
    int idx = 0;
    #pragma unroll
    for (int j = 1; j < 18; j++) idx += (i >= dPO[j]) ? 1 : 0;
    int rel = i - dPO[idx];
    dst[i] = isbf16 ? ((const u16*)p.s[idx])[rel] : f2b(((const float*)p.s[idx])[rel]);
}

// out[f][h] = sum_c W[f*256+h*64+c] * att[h*64+c]
__global__ void proj_weight(const u16* __restrict__ W, const u16* __restrict__ att,
                            float* __restrict__ out, int R) {
    int i = blockIdx.x * 256 + threadIdx.x;
    if (i >= R * 4) return;
    int f = i >> 2, h = i & 3;
    float s = 0.f;
    for (int c = 0; c < 64; c++)
        s += b2f(W[f * 256 + h * 64 + c]) * b2f(att[h * 64 + c]);
    out[i] = s;
}

__global__ void proj_weight2(const u16* __restrict__ W, const u16* __restrict__ atta,
                             const u16* __restrict__ attb,
                             float* __restrict__ outa, float* __restrict__ outb, int R) {
    int i = blockIdx.x * 256 + threadIdx.x;
    if (i >= R * 4) return;
    int f = i >> 2, h = i & 3;
    float sa = 0.f, sb = 0.f;
    for (int c = 0; c < 64; c++) {
        float w = b2f(W[f * 256 + h * 64 + c]);
        sa += w * b2f(atta[h * 64 + c]);
        sb += w * b2f(attb[h * 64 + c]);
    }
    outa[i] = sa;
    outb[i] = sb;
}

// W[K][256] -> WT[256][K]
__global__ void transpose_w(const u16* __restrict__ W, u16* __restrict__ WT, int K) {
    int i = blockIdx.x * 256 + threadIdx.x;
    if (i >= K * 256) return;
    int k = i / 256, c = i % 256;
    WT[c * K + k] = W[i];
}

// ---------------- edge pass: ae per edge (no float atomics) + deg histogram --------
__global__ __launch_bounds__(256) void edge_ae(
    const void* __restrict__ eattr_raw, const int* __restrict__ flag,
    const int* __restrict__ edst,
    const float* __restrict__ ve1, const float* __restrict__ ve2,
    float* __restrict__ ae1, float* __restrict__ ae2, int* __restrict__ deg) {
    int e = blockIdx.x * 256 + threadIdx.x;
    if (e >= NEDGES) return;
    float a[16];
    if (*flag) {
        const u16* s = (const u16*)eattr_raw + (long)e * 16;
        const uint4* p = (const uint4*)s;
        uint4 q0 = p[0], q1 = p[1];
        unsigned w0[8] = {q0.x, q0.y, q0.z, q0.w, q1.x, q1.y, q1.z, q1.w};
        #pragma unroll
        for (int j = 0; j < 8; j++) {
            a[2 * j] = b2f((u16)(w0[j] & 0xffff));
            a[2 * j + 1] = b2f((u16)(w0[j] >> 16));
        }
    } else {
        const float* s = (const float*)eattr_raw + (long)e * 16;
        #pragma unroll
        for (int j = 0; j < 16; j += 4) {
            float4 q = *(const float4*)(s + j);
            a[j] = q.x; a[j + 1] = q.y; a[j + 2] = q.z; a[j + 3] = q.w;
        }
    }
    atomicAdd(&deg[edst[e]], 1);
    #pragma unroll
    for (int h = 0; h < 4; h++) {
        float s1 = 0.f, s2 = 0.f;
        #pragma unroll
        for (int f = 0; f < 16; f++) {
            s1 += a[f] * ve1[f * 4 + h];
            s2 += a[f] * ve2[f * 4 + h];
        }
        ae1[e * 4 + h] = s1;
        ae2[e * 4 + h] = s2;
    }
}

// ---------------- CSR build ----------------
__global__ void block_sum(const int* __restrict__ deg, int* __restrict__ bsums, int n) {
    __shared__ int lds[256];
    int i = blockIdx.x * 256 + threadIdx.x;
    lds[threadIdx.x] = (i < n) ? deg[i] : 0;
    __syncthreads();
    for (int s = 128; s; s >>= 1) {
        if (threadIdx.x < s) lds[threadIdx.x] += lds[threadIdx.x + s];
        __syncthreads();
    }
    if (threadIdx.x == 0) bsums[blockIdx.x] = lds[0];
}

__global__ void scan_bsums(const int* __restrict__ bsums, int* __restrict__ boffs, int nb) {
    __shared__ int lds[256];
    int t = threadIdx.x;
    int v = (t < nb) ? bsums[t] : 0;
    lds[t] = v;
    __syncthreads();
    for (int s = 1; s < 256; s <<= 1) {
        int u = (t >= s) ? lds[t - s] : 0;
        __syncthreads();
        lds[t] += u;
        __syncthreads();
    }
    boffs[t] = lds[t] - v;  // exclusive
}

__global__ void write_offsets(const int* __restrict__ deg, const int* __restrict__ boffs,
                              int* __restrict__ off, int* __restrict__ cursor, int n) {
    __shared__ int lds[256];
    int t = threadIdx.x;
    int i = blockIdx.x * 256 + t;
    int v = (i < n) ? deg[i] : 0;
    lds[t] = v;
    __syncthreads();
    for (int s = 1; s < 256; s <<= 1) {
        int u = (t >= s) ? lds[t - s] : 0;
        __syncthreads();
        lds[t] += u;
        __syncthreads();
    }
    int exc = lds[t] - v + boffs[blockIdx.x];
    if (i < n) { off[i] = exc; cursor[i] = exc; }
}

__global__ void csr_fill(const int* __restrict__ edst, int* __restrict__ cursor,
                         int* __restrict__ edges) {
    int e = blockIdx.x * 256 + threadIdx.x;
    if (e >= NEDGES) return;
    int p = atomicAdd(&cursor[edst[e]], 1);
    edges[p] = e;
}

// ---------------- MFMA GEMM: out[M][256] = A[M][K] @ W[K][256] via WT[256][K] --------
// A-frag: A[m=lane&15][k=quad*8+j]; B-frag: WT[n=lane&15 (+tile)][k=quad*8+j];
// C/D: col=lane&15, row=quad*4+reg  [m89/m91-verified mappings]
template <int K>
__global__ __launch_bounds__(256) void gemm_mfma(const u16* __restrict__ A,
                                                 const u16* __restrict__ WT,
                                                 u16* __restrict__ out) {
    int tid = threadIdx.x;
    int wave = tid >> 6, lane = tid & 63;
    int quad = lane >> 4, l15 = lane & 15;
    long row0 = (long)blockIdx.x * 16;
    const u16* Arow = A + (row0 + l15) * K + quad * 8;
    const u16* Wbase = WT + (long)(wave * 64 + l15) * K + quad * 8;
    f32x4 acc[4] = {};
    for (int kk = 0; kk < K; kk += 32) {
        bf16x8 av = *(const bf16x8*)(Arow + kk);
        #pragma unroll
        for (int nt = 0; nt < 4; nt++) {
            bf16x8 bv = *(const bf16x8*)(Wbase + (long)nt * 16 * K + kk);
            acc[nt] = __builtin_amdgcn_mfma_f32_16x16x32_bf16(av, bv, acc[nt], 0, 0, 0);
        }
    }
    u16* orow = out + row0 * HC;
    #pragma unroll
    for (int nt = 0; nt < 4; nt++) {
        #pragma unroll
        for (int j = 0; j < 4; j++) {
            int r = quad * 4 + j;
            int c = wave * 64 + nt * 16 + l15;
            orow[(long)r * HC + c] = f2b(acc[nt][j]);
        }
    }
}

// ---------------- a_s/a_d projection ----------------
template <int K>
__global__ __launch_bounds__(256) void proj_att(const u16* __restrict__ X,
                                                const float* __restrict__ us,
                                                const float* __restrict__ ud,
                                                float* __restrict__ as_, float* __restrict__ ad_) {
    int wid = (blockIdx.x * 256 + threadIdx.x) >> 6;
    int lane = threadIdx.x & 63;
    if (wid >= NNODES) return;
    float pas[4] = {0.f, 0.f, 0.f, 0.f}, pad[4] = {0.f, 0.f, 0.f, 0.f};
    const u16* row = X + (long)wid * K;
    for (int f = lane; f < K; f += 64) {
        float xv = b2f(row[f]);
        #pragma unroll
        for (int h = 0; h < 4; h++) {
            pas[h] += xv * us[f * 4 + h];
            pad[h] += xv * ud[f * 4 + h];
        }
    }
    #pragma unroll
    for (int h = 0; h < 4; h++) {
        for (int o = 32; o; o >>= 1) {
            pas[h] += __shfl_down(pas[h], o);
            pad[h] += __shfl_down(pad[h], o);
        }
    }
    if (lane == 0) {
        #pragma unroll
        for (int h = 0; h < 4; h++) {
            as_[wid * 4 + h] = pas[h];
            ad_[wid * 4 + h] = pad[h];
        }
    }
}

// ---------------- GAT attention + aggregation (one wave per dst node) --------
// online softmax over edges; self-loop (logit uses sum_ae/deg) merged at the end
__global__ __launch_bounds__(256) void gat_agg(
    const u16* __restrict__ xs, const float* __restrict__ as_, const float* __restrict__ ad_,
    const float* __restrict__ ae,
    const int* __restrict__ off, const int* __restrict__ cur, const int* __restrict__ edges,
    const int* __restrict__ esrc, const u16* __restrict__ bias, u16* __restrict__ out) {
    int wid = (blockIdx.x * 256 + threadIdx.x) >> 6;
    if (wid >= NNODES) return;
    int lane = threadIdx.x & 63;
    int h = lane >> 4;
    int d = wid;
    int st = off[d], en = cur[d];
    float degf = (float)(en - st);
    float adv = ad_[d * 4 + h];
    float asv = as_[d * 4 + h];
    float m = -1e30f, s = 0.f, sae = 0.f;
    float a0 = 0.f, a1 = 0.f, a2 = 0.f, a3 = 0.f;
    for (int i = st; i < en; i++) {
        int e = edges[i];
        int src = esrc[e];
        float aev = ae[e * 4 + h];
        sae += aev;
        float lg = as_[src * 4 + h] + adv + aev;
        lg = (lg > 0.f) ? lg : 0.2f * lg;
        float mn = fmaxf(m, lg);
        float sc = __expf(m - mn), w = __expf(lg - mn);
        uint2 v = *(const uint2*)(xs + (long)src * HC + lane * 4);
        float x0 = b2f((u16)(v.x & 0xffff)), x1 = b2f((u16)(v.x >> 16));
        float x2 = b2f((u16)(v.y & 0xffff)), x3 = b2f((u16)(v.y >> 16));
        s = s * sc + w;
        a0 = a0 * sc + w * x0;
        a1 = a1 * sc + w * x1;
        a2 = a2 * sc + w * x2;
        a3 = a3 * sc + w * x3;
        m = mn;
    }
    // merge self-loop
    {
        float l0 = asv + adv + sae / fmaxf(degf, 1.0f);
        l0 = (l0 > 0.f) ? l0 : 0.2f * l0;
        float mn = fmaxf(m, l0);
        float sc = __expf(m - mn), w = __expf(l0 - mn);
        uint2 v = *(const uint2*)(xs + (long)d * HC + lane * 4);
        float x0 = b2f((u16)(v.x & 0xffff)), x1 = b2f((u16)(v.x >> 16));
        float x2 = b2f((u16)(v.y & 0xffff)), x3 = b2f((u16)(v.y >> 16));
        s = s * sc + w;
        a0 = a0 * sc + w * x0;
        a1 = a1 * sc + w * x1;
        a2 = a2 * sc + w * x2;
        a3 = a3 * sc + w * x3;
    }
    float inv = 1.0f / (s + 1e-16f);
    int cb = lane * 4;
    u16 o0 = f2b(a0 * inv + b2f(bias[cb + 0]));
    u16 o1 = f2b(a1 * inv + b2f(bias[cb + 1]));
    u16 o2 = f2b(a2 * inv + b2f(bias[cb + 2]));
    u16 o3 = f2b(a3 * inv + b2f(bias[cb + 3]));
    uint2 ov;
    ov.x = (unsigned)o0 | ((unsigned)o1 << 16);
    ov.y = (unsigned)o2 | ((unsigned)o3 << 16);
    *(uint2*)(out + (long)d * HC + cb) = ov;
}

// ---------------- BatchNorm (batch stats) + ReLU ----------------
__global__ void bn_stats(const u16* __restrict__ h, float* __restrict__ stats) {
    int c = threadIdx.x;
    float s = 0.f, q = 0.f;
    for (int r = blockIdx.x; r < NNODES; r += gridDim.x) {
        float v = b2f(h[(long)r * HC + c]);
        s += v;
        q += v * v;
    }
    atomicAdd(&stats[c], s);
    atomicAdd(&stats[256 + c], q);
}

__global__ void bn_apply(u16* __restrict__ h, const float* __restrict__ stats,
                         const u16* __restrict__ g, const u16* __restrict__ be) {
    long i = (long)blockIdx.x * 256 + threadIdx.x;
    if (i >= (long)NNODES * HC) return;
    int c = (int)(i & 255);
    float mu = stats[c] * (1.0f / NNODES);
    float var = stats[256 + c] * (1.0f / NNODES) - mu * mu;
    var = fmaxf(var, 0.f);
    float rs = rsqrtf(var + 1e-5f);
    float v = b2f(h[i]);
    float y = b2f(g[c]) * (v - mu) * rs + b2f(be[c]);
    h[i] = f2b(fmaxf(y, 0.f));
}

// ---------------- output head (dtype-dispatched store) ----------------
__global__ __launch_bounds__(256) void out_head(const u16* __restrict__ h,
                                                const u16* __restrict__ wout,
                                                const u16* __restrict__ bout,
                                                void* __restrict__ y,
                                                const int* __restrict__ flag) {
    int wid = (blockIdx.x * 256 + threadIdx.x) >> 6;
    int lane = threadIdx.x & 63;
    if (wid >= NNODES) return;
    const u16* r = h + (long)wid * HC + lane * 4;
    float p = b2f(r[0]) * b2f(wout[lane * 4 + 0]) + b2f(r[1]) * b2f(wout[lane * 4 + 1]) +
              b2f(r[2]) * b2f(wout[lane * 4 + 2]) + b2f(r[3]) * b2f(wout[lane * 4 + 3]);
    for (int o = 32; o; o >>= 1) p += __shfl_down(p, o);
    if (lane == 0) {
        float v = p + b2f(bout[0]);
        if (*flag) ((u16*)y)[wid] = f2b(v);
        else       ((float*)y)[wid] = v;
    }
}

extern "C" void kernel_launch(void* const* d_in, const int* in_sizes, int n_in,
                              void* d_out, int out_size, void* d_ws, size_t ws_size,
                              hipStream_t stream) {
    (void)in_sizes; (void)n_in; (void)out_size; (void)ws_size;
    const void* x_raw     = d_in[0];
    const int*  esrc      = (const int*)d_in[1];
    const int*  edst      = (const int*)d_in[2];
    const void* eattr_raw = d_in[3];

    char* ws = (char*)d_ws;
    size_t o = 0;
    auto alloc = [&](size_t bytes) -> char* {
        o = (o + 255) & ~(size_t)255;
        char* p = ws + o;
        o += bytes;
        return p;
    };
    int* dflag = (int*)alloc(256);
    u16* xb   = (u16*)alloc((size_t)NNODES * 64 * 2);
    u16* pall = (u16*)alloc((size_t)TOTP * 2);
    u16 *W1b = pall + hPO[0], *atts1b = pall + hPO[1], *attd1b = pall + hPO[2],
        *We1b = pall + hPO[3], *atte1b = pall + hPO[4], *b1b = pall + hPO[5],
        *g1b = pall + hPO[6], *be1b = pall + hPO[7], *W2b = pall + hPO[8],
        *atts2b = pall + hPO[9], *attd2b = pall + hPO[10], *We2b = pall + hPO[11],
        *atte2b = pall + hPO[12], *b2b = pall + hPO[13], *g2b = pall + hPO[14],
        *be2b = pall + hPO[15], *Woutb = pall + hPO[16], *boutb = pall + hPO[17];
    u16* WT1 = (u16*)alloc(256 * 64 * 2);
    u16* WT2 = (u16*)alloc(256 * 256 * 2);
    float* ve1 = (float*)alloc(64 * 4);
    float* ve2 = (float*)alloc(64 * 4);
    float* us1 = (float*)alloc(256 * 4);
    float* ud1 = (float*)alloc(256 * 4);
    float* us2 = (float*)alloc(1024 * 4);
    float* ud2 = (float*)alloc(1024 * 4);
    // zero zone: deg + stats
    int* deg = (int*)alloc((size_t)NNODES * 4);
    float* stats1 = (float*)alloc(512 * 4);
    float* stats2 = (float*)alloc(512 * 4);
    size_t zero_end = o;
    size_t zero_begin = (size_t)((char*)deg - ws);
    // rest
    int* off = (int*)alloc((size_t)NNODES * 4);
    int* cursor = (int*)alloc((size_t)NNODES * 4);
    int* bsums = (int*)alloc(256 * 4);
    int* boffs = (int*)alloc(256 * 4);
    int* csr = (int*)alloc((size_t)NEDGES * 4);
    float* ae1 = (float*)alloc((size_t)NEDGES * 16);
    float* ae2 = (float*)alloc((size_t)NEDGES * 16);
    float* as_ = (float*)alloc((size_t)NNODES * 16);
    float* ad_ = (float*)alloc((size_t)NNODES * 16);
    u16* bufA = (u16*)alloc((size_t)NNODES * HC * 2);  // xs1, then xs2
    u16* bufB = (u16*)alloc((size_t)NNODES * HC * 2);  // h1, then h2

    long zwords = (long)((zero_end - zero_begin) / 4);
    zero_init<<<128, 256, 0, stream>>>((unsigned*)(ws + zero_begin), zwords);
    detect_dtype<<<1, 256, 0, stream>>>((const unsigned*)x_raw, dflag);

    cvt_bf16<<<2048, 256, 0, stream>>>(x_raw, xb, NNODES * 64, dflag);
    Ptrs18 pp;
    for (int i = 0; i < 18; i++) pp.s[i] = d_in[4 + i];
    cvt_params<<<(TOTP + 255) / 256, 256, 0, stream>>>(pp, pall, dflag);

    transpose_w<<<64, 256, 0, stream>>>(W1b, WT1, 64);
    transpose_w<<<256, 256, 0, stream>>>(W2b, WT2, 256);
    proj_weight<<<1, 256, 0, stream>>>(We1b, atte1b, ve1, 16);
    proj_weight<<<1, 256, 0, stream>>>(We2b, atte2b, ve2, 16);
    proj_weight2<<<1, 256, 0, stream>>>(W1b, atts1b, attd1b, us1, ud1, 64);
    proj_weight2<<<4, 256, 0, stream>>>(W2b, atts2b, attd2b, us2, ud2, 256);

    int eblocks = (NEDGES + 255) / 256;
    edge_ae<<<eblocks, 256, 0, stream>>>(eattr_raw, dflag, edst, ve1, ve2, ae1, ae2, deg);
    int nb = (NNODES + 255) / 256;  // 196
    block_sum<<<nb, 256, 0, stream>>>(deg, bsums, NNODES);
    scan_bsums<<<1, 256, 0, stream>>>(bsums, boffs, nb);
    write_offsets<<<nb, 256, 0, stream>>>(deg, boffs, off, cursor, NNODES);
    csr_fill<<<eblocks, 256, 0, stream>>>(edst, cursor, csr);

    int mtiles = NNODES / 16;                 // 3125
    int wblocks = (NNODES * 64 + 255) / 256;  // 12500

    // layer 1 (xb: K=64)
    gemm_mfma<64><<<mtiles, 256, 0, stream>>>(xb, WT1, bufA);
    proj_att<64><<<wblocks, 256, 0, stream>>>(xb, us1, ud1, as_, ad_);
    gat_agg<<<wblocks, 256, 0, stream>>>(bufA, as_, ad_, ae1, off, cursor, csr, esrc, b1b, bufB);
    bn_stats<<<1024, 256, 0, stream>>>(bufB, stats1);
    bn_apply<<<(NNODES * HC + 255) / 256, 256, 0, stream>>>(bufB, stats1, g1b, be1b);

    // layer 2 (h1 = bufB: K=256)
    gemm_mfma<256><<<mtiles, 256, 0, stream>>>(bufB, WT2, bufA);
    proj_att<256><<<wblocks, 256, 0, stream>>>(bufB, us2, ud2, as_, ad_);
    gat_agg<<<wblocks, 256, 0, stream>>>(bufA, as_, ad_, ae2, off, cursor, csr, esrc, b2b, bufB);
    bn_stats<<<1024, 256, 0, stream>>>(bufB, stats2);
    bn_apply<<<(NNODES * HC + 255) / 256, 256, 0, stream>>>(bufB, stats2, g2b, be2b);

    out_head<<<wblocks, 256, 0, stream>>>(bufB, Woutb, boutb, d_out, dflag);
}

// Round 6
// 680.964 us; speedup vs baseline: 1.7913x; 1.1557x over previous
//
#include <hip/hip_runtime.h>
#include <hip/hip_bf16.h>
#include <stdint.h>

#define NNODES 50000
#define NEDGES 800000
#define HC 256

typedef unsigned short u16;
typedef __attribute__((ext_vector_type(8))) short bf16x8;
typedef __attribute__((ext_vector_type(4))) float f32x4;

__device__ __forceinline__ float b2f(u16 v) {
    return __uint_as_float(((unsigned)v) << 16);
}
__device__ __forceinline__ u16 f2b(float f) {
    unsigned u = __float_as_uint(f);
    u += 0x7fff + ((u >> 16) & 1);
    return (u16)(u >> 16);
}

// param table: W1,atts1,attd1,We1,atte1,b1,g1,be1,W2,atts2,attd2,We2,atte2,b2,g2,be2,Wout,bout
__device__ __constant__ int dPO[19] = {0,16384,16640,16896,20992,21248,21504,21760,22016,
                                       87552,87808,88064,92160,92416,92672,92928,93184,93440,93441};
static const int hPO[19] = {0,16384,16640,16896,20992,21248,21504,21760,22016,
                            87552,87808,88064,92160,92416,92672,92928,93184,93440,93441};
#define TOTP 93441

__global__ void zero_init(unsigned* __restrict__ p, long nwords) {
    long i = (long)blockIdx.x * blockDim.x + threadIdx.x;
    long stride = (long)gridDim.x * blockDim.x;
    for (; i < nwords; i += stride) p[i] = 0u;
}

// 1 = bf16 inputs, 0 = fp32 inputs
__global__ void detect_dtype(const unsigned* __restrict__ xbits, int* __restrict__ flag) {
    __shared__ int cnt;
    if (threadIdx.x == 0) cnt = 0;
    __syncthreads();
    int sane = 0;
    for (int i = threadIdx.x; i < 1024; i += 256) {
        unsigned lo = xbits[i] & 0xffffu;
        int e = (int)((lo >> 7) & 0xff);
        if (e >= 117 && e <= 133) sane++;
    }
    atomicAdd(&cnt, sane);
    __syncthreads();
    if (threadIdx.x == 0) *flag = (cnt >= 512) ? 1 : 0;
}

__global__ void cvt_bf16(const void* __restrict__ src, u16* __restrict__ dst, int n,
                         const int* __restrict__ flag) {
    int isbf16 = *flag;
    int i = blockIdx.x * 256 + threadIdx.x;
    int stride = gridDim.x * 256;
    if (isbf16) {
        const u16* s = (const u16*)src;
        for (; i < n; i += stride) dst[i] = s[i];
    } else {
        const float* s = (const float*)src;
        for (; i < n; i += stride) dst[i] = f2b(s[i]);
    }
}

struct Ptrs18 { const void* s[18]; };
__global__ void cvt_params(Ptrs18 p, u16* __restrict__ dst, const int* __restrict__ flag) {
    int i = blockIdx.x * 256 + threadIdx.x;
    if (i >= TOTP) return;
    int isbf16 = *flag;
    int idx = 0;
    #pragma unroll
    for (int j = 1; j < 18; j++) idx += (i >= dPO[j]) ? 1 : 0;
    int rel = i - dPO[idx];
    dst[i] = isbf16 ? ((const u16*)p.s[idx])[rel] : f2b(((const float*)p.s[idx])[rel]);
}

__global__ void proj_weight(const u16* __restrict__ W, const u16* __restrict__ att,
                            float* __restrict__ out, int R) {
    int i = blockIdx.x * 256 + threadIdx.x;
    if (i >= R * 4) return;
    int f = i >> 2, h = i & 3;
    float s = 0.f;
    for (int c = 0; c < 64; c++)
        s += b2f(W[f * 256 + h * 64 + c]) * b2f(att[h * 64 + c]);
    out[i] = s;
}

__global__ void proj_weight2(const u16* __restrict__ W, const u16* __restrict__ atta,
                             const u16* __restrict__ attb,
                             float* __restrict__ outa, float* __restrict__ outb, int R) {
    int i = blockIdx.x * 256 + threadIdx.x;
    if (i >= R * 4) return;
    int f = i >> 2, h = i & 3;
    float sa = 0.f, sb = 0.f;
    for (int c = 0; c < 64; c++) {
        float w = b2f(W[f * 256 + h * 64 + c]);
        sa += w * b2f(atta[h * 64 + c]);
        sb += w * b2f(attb[h * 64 + c]);
    }
    outa[i] = sa;
    outb[i] = sb;
}

// W[K][256] -> WT[256][K]
__global__ void transpose_w(const u16* __restrict__ W, u16* __restrict__ WT, int K) {
    int i = blockIdx.x * 256 + threadIdx.x;
    if (i >= K * 256) return;
    int k = i / 256, c = i % 256;
    WT[c * K + k] = W[i];
}

// ---------------- degree histogram ----------------
__global__ void edge_deg(const int* __restrict__ edst, int* __restrict__ deg) {
    int e = blockIdx.x * 256 + threadIdx.x;
    if (e >= NEDGES) return;
    atomicAdd(&deg[edst[e]], 1);
}

// ---------------- CSR scan ----------------
__global__ void block_sum(const int* __restrict__ deg, int* __restrict__ bsums, int n) {
    __shared__ int lds[256];
    int i = blockIdx.x * 256 + threadIdx.x;
    lds[threadIdx.x] = (i < n) ? deg[i] : 0;
    __syncthreads();
    for (int s = 128; s; s >>= 1) {
        if (threadIdx.x < s) lds[threadIdx.x] += lds[threadIdx.x + s];
        __syncthreads();
    }
    if (threadIdx.x == 0) bsums[blockIdx.x] = lds[0];
}

__global__ void scan_bsums(const int* __restrict__ bsums, int* __restrict__ boffs, int nb) {
    __shared__ int lds[256];
    int t = threadIdx.x;
    int v = (t < nb) ? bsums[t] : 0;
    lds[t] = v;
    __syncthreads();
    for (int s = 1; s < 256; s <<= 1) {
        int u = (t >= s) ? lds[t - s] : 0;
        __syncthreads();
        lds[t] += u;
        __syncthreads();
    }
    boffs[t] = lds[t] - v;  // exclusive
}

__global__ void write_offsets(const int* __restrict__ deg, const int* __restrict__ boffs,
                              int* __restrict__ off, int* __restrict__ cursor, int n) {
    __shared__ int lds[256];
    int t = threadIdx.x;
    int i = blockIdx.x * 256 + t;
    int v = (i < n) ? deg[i] : 0;
    lds[t] = v;
    __syncthreads();
    for (int s = 1; s < 256; s <<= 1) {
        int u = (t >= s) ? lds[t - s] : 0;
        __syncthreads();
        lds[t] += u;
        __syncthreads();
    }
    int exc = lds[t] - v + boffs[blockIdx.x];
    if (i < n) { off[i] = exc; cursor[i] = exc; }
}

// ---------------- edge stage: ae per edge, written in CSR order + src ----------------
__global__ __launch_bounds__(256) void edge_stage(
    const void* __restrict__ eattr_raw, const int* __restrict__ flag,
    const int* __restrict__ esrc, const int* __restrict__ edst,
    const float* __restrict__ ve1, const float* __restrict__ ve2,
    int* __restrict__ cursor, int* __restrict__ srcc,
    float* __restrict__ aec1, float* __restrict__ aec2) {
    int e = blockIdx.x * 256 + threadIdx.x;
    if (e >= NEDGES) return;
    float a[16];
    if (*flag) {
        const u16* s = (const u16*)eattr_raw + (long)e * 16;
        const uint4* p = (const uint4*)s;
        uint4 q0 = p[0], q1 = p[1];
        unsigned w0[8] = {q0.x, q0.y, q0.z, q0.w, q1.x, q1.y, q1.z, q1.w};
        #pragma unroll
        for (int j = 0; j < 8; j++) {
            a[2 * j] = b2f((u16)(w0[j] & 0xffff));
            a[2 * j + 1] = b2f((u16)(w0[j] >> 16));
        }
    } else {
        const float* s = (const float*)eattr_raw + (long)e * 16;
        #pragma unroll
        for (int j = 0; j < 16; j += 4) {
            float4 q = *(const float4*)(s + j);
            a[j] = q.x; a[j + 1] = q.y; a[j + 2] = q.z; a[j + 3] = q.w;
        }
    }
    float4 s1, s2;
    float* s1p = (float*)&s1;
    float* s2p = (float*)&s2;
    #pragma unroll
    for (int h = 0; h < 4; h++) {
        float t1 = 0.f, t2 = 0.f;
        #pragma unroll
        for (int f = 0; f < 16; f++) {
            t1 += a[f] * ve1[f * 4 + h];
            t2 += a[f] * ve2[f * 4 + h];
        }
        s1p[h] = t1;
        s2p[h] = t2;
    }
    int d = edst[e];
    int p = atomicAdd(&cursor[d], 1);
    srcc[p] = esrc[e];
    *(float4*)(aec1 + (long)p * 4) = s1;
    *(float4*)(aec2 + (long)p * 4) = s2;
}

// ---------------- MFMA GEMM: out[M][256] = A[M][K] @ W[K][256] via WT[256][K] --------
template <int K>
__global__ __launch_bounds__(256) void gemm_mfma(const u16* __restrict__ A,
                                                 const u16* __restrict__ WT,
                                                 u16* __restrict__ out) {
    int tid = threadIdx.x;
    int wave = tid >> 6, lane = tid & 63;
    int quad = lane >> 4, l15 = lane & 15;
    long row0 = (long)blockIdx.x * 16;
    const u16* Arow = A + (row0 + l15) * K + quad * 8;
    const u16* Wbase = WT + (long)(wave * 64 + l15) * K + quad * 8;
    f32x4 acc[4] = {};
    for (int kk = 0; kk < K; kk += 32) {
        bf16x8 av = *(const bf16x8*)(Arow + kk);
        #pragma unroll
        for (int nt = 0; nt < 4; nt++) {
            bf16x8 bv = *(const bf16x8*)(Wbase + (long)nt * 16 * K + kk);
            acc[nt] = __builtin_amdgcn_mfma_f32_16x16x32_bf16(av, bv, acc[nt], 0, 0, 0);
        }
    }
    u16* orow = out + row0 * HC;
    #pragma unroll
    for (int nt = 0; nt < 4; nt++) {
        #pragma unroll
        for (int j = 0; j < 4; j++) {
            int r = quad * 4 + j;
            int c = wave * 64 + nt * 16 + l15;
            orow[(long)r * HC + c] = f2b(acc[nt][j]);
        }
    }
}

// ---------------- a_s/a_d projection ----------------
template <int K>
__global__ __launch_bounds__(256) void proj_att(const u16* __restrict__ X,
                                                const float* __restrict__ us,
                                                const float* __restrict__ ud,
                                                float* __restrict__ as_, float* __restrict__ ad_) {
    int wid = (blockIdx.x * 256 + threadIdx.x) >> 6;
    int lane = threadIdx.x & 63;
    if (wid >= NNODES) return;
    float pas[4] = {0.f, 0.f, 0.f, 0.f}, pad[4] = {0.f, 0.f, 0.f, 0.f};
    const u16* row = X + (long)wid * K;
    for (int f = lane; f < K; f += 64) {
        float xv = b2f(row[f]);
        #pragma unroll
        for (int h = 0; h < 4; h++) {
            pas[h] += xv * us[f * 4 + h];
            pad[h] += xv * ud[f * 4 + h];
        }
    }
    #pragma unroll
    for (int h = 0; h < 4; h++) {
        for (int o = 32; o; o >>= 1) {
            pas[h] += __shfl_down(pas[h], o);
            pad[h] += __shfl_down(pad[h], o);
        }
    }
    if (lane == 0) {
        #pragma unroll
        for (int h = 0; h < 4; h++) {
            as_[wid * 4 + h] = pas[h];
            ad_[wid * 4 + h] = pad[h];
        }
    }
}

// ---------------- fused GAT attention: phase1 (m,s per head), phase2 gather ----------
// one wave per dst node
__global__ __launch_bounds__(256) void gat_fused(
    const u16* __restrict__ xs, const float* __restrict__ as_, const float* __restrict__ ad_,
    const float* __restrict__ aec, const int* __restrict__ srcc,
    const int* __restrict__ off, const int* __restrict__ deg,
    const u16* __restrict__ bias, u16* __restrict__ out) {
    int wid = (blockIdx.x * 256 + threadIdx.x) >> 6;
    if (wid >= NNODES) return;
    int lane = threadIdx.x & 63;
    int d = wid;
    int st = off[d], dg = deg[d];

    // ---- phase 1: lanes = 16 edge-slots x 4 heads ----
    int slot = lane >> 2, h = lane & 3;
    float adv = ad_[d * 4 + h];
    float m = -1e30f, s = 0.f, sae = 0.f;
    for (int base = 0; base < dg; base += 16) {
        int i = base + slot;
        float lg = -1e30f, aev = 0.f, w = 0.f;
        if (i < dg) {
            int p = st + i;
            int src = srcc[p];
            aev = aec[(long)p * 4 + h];
            float t = as_[src * 4 + h] + adv + aev;
            lg = (t > 0.f) ? t : 0.2f * t;
        }
        sae += aev;
        float mn = fmaxf(m, lg);
        if (i < dg) w = __expf(lg - mn);
        s = s * __expf(m - mn) + w;
        m = mn;
    }
    #pragma unroll
    for (int o = 4; o < 64; o <<= 1) {
        float mo = __shfl_xor(m, o), so = __shfl_xor(s, o), ao = __shfl_xor(sae, o);
        float mn = fmaxf(m, mo);
        s = s * __expf(m - mn) + so * __expf(mo - mn);
        m = mn;
        sae += ao;
    }
    // self-loop logit
    {
        float asv = as_[d * 4 + h];
        float l0 = asv + adv + sae / fmaxf((float)dg, 1.f);
        l0 = (l0 > 0.f) ? l0 : 0.2f * l0;
        float mn = fmaxf(m, l0);
        s = s * __expf(m - mn) + __expf(l0 - mn);
        m = mn;
        float invs = 1.f / s;
        float wself = __expf(l0 - mn) * invs;
        // stash for phase 2 (reuse regs via shuffles below)
        sae = wself;   // sae now = wself
        s = invs;      // s now = invs
    }

    // ---- phase 2: lanes = 64 channel groups (4 ch each) ----
    int h2 = lane >> 4;
    float m2  = __shfl(m, h2);
    float is2 = __shfl(s, h2);
    float ws2 = __shfl(sae, h2);
    float adv2 = __shfl(adv, h2);
    int cb = lane * 4;
    const u16* xrow = xs + (long)d * HC + cb;
    float a0, a1, a2, a3;
    {
        uint2 v = *(const uint2*)xrow;
        a0 = ws2 * b2f((u16)(v.x & 0xffff));
        a1 = ws2 * b2f((u16)(v.x >> 16));
        a2 = ws2 * b2f((u16)(v.y & 0xffff));
        a3 = ws2 * b2f((u16)(v.y >> 16));
    }
    int en = st + dg;
    int i = st;
    for (; i + 4 <= en; i += 4) {
        int s0 = srcc[i], s1 = srcc[i + 1], s2v = srcc[i + 2], s3 = srcc[i + 3];
        float e0 = aec[(long)i * 4 + h2];
        float e1 = aec[(long)(i + 1) * 4 + h2];
        float e2 = aec[(long)(i + 2) * 4 + h2];
        float e3 = aec[(long)(i + 3) * 4 + h2];
        float t0 = as_[s0 * 4 + h2] + adv2 + e0; t0 = (t0 > 0.f) ? t0 : 0.2f * t0;
        float t1 = as_[s1 * 4 + h2] + adv2 + e1; t1 = (t1 > 0.f) ? t1 : 0.2f * t1;
        float t2 = as_[s2v * 4 + h2] + adv2 + e2; t2 = (t2 > 0.f) ? t2 : 0.2f * t2;
        float t3 = as_[s3 * 4 + h2] + adv2 + e3; t3 = (t3 > 0.f) ? t3 : 0.2f * t3;
        float w0 = __expf(t0 - m2) * is2;
        float w1 = __expf(t1 - m2) * is2;
        float w2 = __expf(t2 - m2) * is2;
        float w3 = __expf(t3 - m2) * is2;
        uint2 v0 = *(const uint2*)(xs + (long)s0 * HC + cb);
        uint2 v1 = *(const uint2*)(xs + (long)s1 * HC + cb);
        uint2 v2 = *(const uint2*)(xs + (long)s2v * HC + cb);
        uint2 v3 = *(const uint2*)(xs + (long)s3 * HC + cb);
        a0 += w0 * b2f((u16)(v0.x & 0xffff)) + w1 * b2f((u16)(v1.x & 0xffff))
            + w2 * b2f((u16)(v2.x & 0xffff)) + w3 * b2f((u16)(v3.x & 0xffff));
        a1 += w0 * b2f((u16)(v0.x >> 16)) + w1 * b2f((u16)(v1.x >> 16))
            + w2 * b2f((u16)(v2.x >> 16)) + w3 * b2f((u16)(v3.x >> 16));
        a2 += w0 * b2f((u16)(v0.y & 0xffff)) + w1 * b2f((u16)(v1.y & 0xffff))
            + w2 * b2f((u16)(v2.y & 0xffff)) + w3 * b2f((u16)(v3.y & 0xffff));
        a3 += w0 * b2f((u16)(v0.y >> 16)) + w1 * b2f((u16)(v1.y >> 16))
            + w2 * b2f((u16)(v2.y >> 16)) + w3 * b2f((u16)(v3.y >> 16));
    }
    for (; i < en; i++) {
        int s0 = srcc[i];
        float t0 = as_[s0 * 4 + h2] + adv2 + aec[(long)i * 4 + h2];
        t0 = (t0 > 0.f) ? t0 : 0.2f * t0;
        float w0 = __expf(t0 - m2) * is2;
        uint2 v0 = *(const uint2*)(xs + (long)s0 * HC + cb);
        a0 += w0 * b2f((u16)(v0.x & 0xffff));
        a1 += w0 * b2f((u16)(v0.x >> 16));
        a2 += w0 * b2f((u16)(v0.y & 0xffff));
        a3 += w0 * b2f((u16)(v0.y >> 16));
    }
    u16 o0 = f2b(a0 + b2f(bias[cb + 0]));
    u16 o1 = f2b(a1 + b2f(bias[cb + 1]));
    u16 o2 = f2b(a2 + b2f(bias[cb + 2]));
    u16 o3 = f2b(a3 + b2f(bias[cb + 3]));
    uint2 ov;
    ov.x = (unsigned)o0 | ((unsigned)o1 << 16);
    ov.y = (unsigned)o2 | ((unsigned)o3 << 16);
    *(uint2*)(out + (long)d * HC + cb) = ov;
}

// ---------------- BatchNorm (batch stats) + ReLU ----------------
__global__ void bn_stats(const u16* __restrict__ h, float* __restrict__ stats) {
    int c = threadIdx.x;
    float s = 0.f, q = 0.f;
    for (int r = blockIdx.x; r < NNODES; r += gridDim.x) {
        float v = b2f(h[(long)r * HC + c]);
        s += v;
        q += v * v;
    }
    atomicAdd(&stats[c], s);
    atomicAdd(&stats[256 + c], q);
}

__global__ void bn_apply(u16* __restrict__ h, const float* __restrict__ stats,
                         const u16* __restrict__ g, const u16* __restrict__ be) {
    long i = (long)blockIdx.x * 256 + threadIdx.x;
    if (i >= (long)NNODES * HC) return;
    int c = (int)(i & 255);
    float mu = stats[c] * (1.0f / NNODES);
    float var = stats[256 + c] * (1.0f / NNODES) - mu * mu;
    var = fmaxf(var, 0.f);
    float rs = rsqrtf(var + 1e-5f);
    float v = b2f(h[i]);
    float y = b2f(g[c]) * (v - mu) * rs + b2f(be[c]);
    h[i] = f2b(fmaxf(y, 0.f));
}

// ---------------- output head ----------------
__global__ __launch_bounds__(256) void out_head(const u16* __restrict__ h,
                                                const u16* __restrict__ wout,
                                                const u16* __restrict__ bout,
                                                void* __restrict__ y,
                                                const int* __restrict__ flag) {
    int wid = (blockIdx.x * 256 + threadIdx.x) >> 6;
    int lane = threadIdx.x & 63;
    if (wid >= NNODES) return;
    const u16* r = h + (long)wid * HC + lane * 4;
    float p = b2f(r[0]) * b2f(wout[lane * 4 + 0]) + b2f(r[1]) * b2f(wout[lane * 4 + 1]) +
              b2f(r[2]) * b2f(wout[lane * 4 + 2]) + b2f(r[3]) * b2f(wout[lane * 4 + 3]);
    for (int o = 32; o; o >>= 1) p += __shfl_down(p, o);
    if (lane == 0) {
        float v = p + b2f(bout[0]);
        if (*flag) ((u16*)y)[wid] = f2b(v);
        else       ((float*)y)[wid] = v;
    }
}

extern "C" void kernel_launch(void* const* d_in, const int* in_sizes, int n_in,
                              void* d_out, int out_size, void* d_ws, size_t ws_size,
                              hipStream_t stream) {
    (void)in_sizes; (void)n_in; (void)out_size; (void)ws_size;
    const void* x_raw     = d_in[0];
    const int*  esrc      = (const int*)d_in[1];
    const int*  edst      = (const int*)d_in[2];
    const void* eattr_raw = d_in[3];

    char* ws = (char*)d_ws;
    size_t o = 0;
    auto alloc = [&](size_t bytes) -> char* {
        o = (o + 255) & ~(size_t)255;
        char* p = ws + o;
        o += bytes;
        return p;
    };
    int* dflag = (int*)alloc(256);
    u16* xb   = (u16*)alloc((size_t)NNODES * 64 * 2);
    u16* pall = (u16*)alloc((size_t)TOTP * 2);
    u16 *W1b = pall + hPO[0], *atts1b = pall + hPO[1], *attd1b = pall + hPO[2],
        *We1b = pall + hPO[3], *atte1b = pall + hPO[4], *b1b = pall + hPO[5],
        *g1b = pall + hPO[6], *be1b = pall + hPO[7], *W2b = pall + hPO[8],
        *atts2b = pall + hPO[9], *attd2b = pall + hPO[10], *We2b = pall + hPO[11],
        *atte2b = pall + hPO[12], *b2b = pall + hPO[13], *g2b = pall + hPO[14],
        *be2b = pall + hPO[15], *Woutb = pall + hPO[16], *boutb = pall + hPO[17];
    u16* WT1 = (u16*)alloc(256 * 64 * 2);
    u16* WT2 = (u16*)alloc(256 * 256 * 2);
    float* ve1 = (float*)alloc(64 * 4);
    float* ve2 = (float*)alloc(64 * 4);
    float* us1 = (float*)alloc(256 * 4);
    float* ud1 = (float*)alloc(256 * 4);
    float* us2 = (float*)alloc(1024 * 4);
    float* ud2 = (float*)alloc(1024 * 4);
    // zero zone: deg + stats
    int* deg = (int*)alloc((size_t)NNODES * 4);
    float* stats1 = (float*)alloc(512 * 4);
    float* stats2 = (float*)alloc(512 * 4);
    size_t zero_end = o;
    size_t zero_begin = (size_t)((char*)deg - ws);
    // rest
    int* off = (int*)alloc((size_t)NNODES * 4);
    int* cursor = (int*)alloc((size_t)NNODES * 4);
    int* bsums = (int*)alloc(256 * 4);
    int* boffs = (int*)alloc(256 * 4);
    int* srcc = (int*)alloc((size_t)NEDGES * 4);
    float* aec1 = (float*)alloc((size_t)NEDGES * 16);
    float* aec2 = (float*)alloc((size_t)NEDGES * 16);
    float* as_ = (float*)alloc((size_t)NNODES * 16);
    float* ad_ = (float*)alloc((size_t)NNODES * 16);
    u16* bufA = (u16*)alloc((size_t)NNODES * HC * 2);  // xs1, then xs2
    u16* bufB = (u16*)alloc((size_t)NNODES * HC * 2);  // h1, then h2

    long zwords = (long)((zero_end - zero_begin) / 4);
    zero_init<<<128, 256, 0, stream>>>((unsigned*)(ws + zero_begin), zwords);
    detect_dtype<<<1, 256, 0, stream>>>((const unsigned*)x_raw, dflag);

    cvt_bf16<<<2048, 256, 0, stream>>>(x_raw, xb, NNODES * 64, dflag);
    Ptrs18 pp;
    for (int i = 0; i < 18; i++) pp.s[i] = d_in[4 + i];
    cvt_params<<<(TOTP + 255) / 256, 256, 0, stream>>>(pp, pall, dflag);

    transpose_w<<<64, 256, 0, stream>>>(W1b, WT1, 64);
    transpose_w<<<256, 256, 0, stream>>>(W2b, WT2, 256);
    proj_weight<<<1, 256, 0, stream>>>(We1b, atte1b, ve1, 16);
    proj_weight<<<1, 256, 0, stream>>>(We2b, atte2b, ve2, 16);
    proj_weight2<<<1, 256, 0, stream>>>(W1b, atts1b, attd1b, us1, ud1, 64);
    proj_weight2<<<4, 256, 0, stream>>>(W2b, atts2b, attd2b, us2, ud2, 256);

    int eblocks = (NEDGES + 255) / 256;
    int nb = (NNODES + 255) / 256;  // 196
    edge_deg<<<eblocks, 256, 0, stream>>>(edst, deg);
    block_sum<<<nb, 256, 0, stream>>>(deg, bsums, NNODES);
    scan_bsums<<<1, 256, 0, stream>>>(bsums, boffs, nb);
    write_offsets<<<nb, 256, 0, stream>>>(deg, boffs, off, cursor, NNODES);
    edge_stage<<<eblocks, 256, 0, stream>>>(eattr_raw, dflag, esrc, edst, ve1, ve2,
                                            cursor, srcc, aec1, aec2);

    int mtiles = NNODES / 16;                 // 3125
    int wblocks = (NNODES * 64 + 255) / 256;  // 12500

    // layer 1 (xb: K=64)
    gemm_mfma<64><<<mtiles, 256, 0, stream>>>(xb, WT1, bufA);
    proj_att<64><<<wblocks, 256, 0, stream>>>(xb, us1, ud1, as_, ad_);
    gat_fused<<<wblocks, 256, 0, stream>>>(bufA, as_, ad_, aec1, srcc, off, deg, b1b, bufB);
    bn_stats<<<256, 256, 0, stream>>>(bufB, stats1);
    bn_apply<<<(NNODES * HC + 255) / 256, 256, 0, stream>>>(bufB, stats1, g1b, be1b);

    // layer 2 (h1 = bufB: K=256)
    gemm_mfma<256><<<mtiles, 256, 0, stream>>>(bufB, WT2, bufA);
    proj_att<256><<<wblocks, 256, 0, stream>>>(bufB, us2, ud2, as_, ad_);
    gat_fused<<<wblocks, 256, 0, stream>>>(bufA, as_, ad_, aec2, srcc, off, deg, b2b, bufB);
    bn_stats<<<256, 256, 0, stream>>>(bufB, stats2);
    bn_apply<<<(NNODES * HC + 255) / 256, 256, 0, stream>>>(bufB, stats2, g2b, be2b);

    out_head<<<wblocks, 256, 0, stream>>>(bufB, Woutb, boutb, d_out, dflag);
}